// Round 5
// baseline (1763.182 us; speedup 1.0000x reference)
//
#include <hip/hip_runtime.h>
#include <cstdint>

#define F_IN  128
#define F_HID 16
#define F_OUT 138
#define DSTB_SHIFT 9
#define NPB 512                  // nodes per dst bucket
#define NDSTB 256                // dst buckets (196 used at n=100000)
#define SRC_SHIFT 14
#define NSLICE 8                 // src slices of 16384 nodes (7 used)
#define NSEG (NDSTB * NSLICE)    // 2048 segments
#define NB 256                   // edge slabs for binning passes

// ---------------------------------------------------------------------------
// Detect edge_index dtype: int64 (LE, values < 2^31) -> every odd int32 word
// is zero. flag = 1 -> int64 (stride 2 int32 words), 0 -> int32.
__global__ void k_detect(const int* __restrict__ idx, int* __restrict__ flag) {
    __shared__ int nz;
    if (threadIdx.x == 0) nz = 0;
    __syncthreads();
    for (int i = threadIdx.x; i < 1024; i += blockDim.x)
        if (idx[2 * i + 1] != 0) nz = 1;
    __syncthreads();
    if (threadIdx.x == 0) *flag = (nz == 0) ? 1 : 0;
}

// Pass A: per-slab LDS histogram over 2048 (dstb,slice) segments.
// cnt layout is BLOCK-MAJOR: cnt[b*NSEG + seg] (coalesced writes here,
// coalesced per-b reads in k_scanA).
__global__ void k_bincount(const int* __restrict__ idx, const int* __restrict__ flag,
                           unsigned* __restrict__ cnt, int E) {
    __shared__ unsigned hist[NSEG];   // 8 KB
    int tid = threadIdx.x;
    for (int i = tid; i < NSEG; i += 256) hist[i] = 0;
    __syncthreads();
    const int mult = 1 + *flag;
    int slab = (E + NB - 1) / NB;
    int start = blockIdx.x * slab, end = min(E, start + slab);
    if (mult == 2) {
        for (int e = start + tid; e < end; e += 256) {
            int s = ((const int2*)idx)[e].x;
            int d = ((const int2*)idx)[(size_t)E + e].x;
            atomicAdd(&hist[((d >> DSTB_SHIFT) << 3) | (s >> SRC_SHIFT)], 1u);
        }
    } else {
        for (int e = start + tid; e < end; e += 256) {
            int s = idx[e];
            int d = idx[(size_t)E + e];
            atomicAdd(&hist[((d >> DSTB_SHIFT) << 3) | (s >> SRC_SHIFT)], 1u);
        }
    }
    __syncthreads();
    for (int i = tid; i < NSEG; i += 256) cnt[(size_t)blockIdx.x * NSEG + i] = hist[i];
}

// Scan step 1: per segment, exclusive-scan its 256 slab counts in place;
// emit per-segment total. thread = seg (8 blocks x 256).
__global__ void k_scanA(unsigned* __restrict__ cnt, unsigned* __restrict__ segTot) {
    int seg = blockIdx.x * 256 + threadIdx.x;
    unsigned run = 0;
    for (int b = 0; b < NB; ++b) {
        unsigned c = cnt[(size_t)b * NSEG + seg];
        cnt[(size_t)b * NSEG + seg] = run;
        run += c;
    }
    segTot[seg] = run;
}

// Scan step 2: exclusive scan of 2048 segment totals -> segBase, segPtr.
__global__ void k_scanB(const unsigned* __restrict__ segTot,
                        unsigned* __restrict__ segBase, unsigned* __restrict__ segPtr) {
    __shared__ unsigned sums[256];
    int t = threadIdx.x;
    unsigned loc[8];
    unsigned s = 0;
#pragma unroll
    for (int k = 0; k < 8; ++k) { loc[k] = segTot[t * 8 + k]; s += loc[k]; }
    sums[t] = s;
    __syncthreads();
    for (int off = 1; off < 256; off <<= 1) {
        unsigned v = (t >= off) ? sums[t - off] : 0u;
        __syncthreads();
        sums[t] += v;
        __syncthreads();
    }
    unsigned base = sums[t] - s;
#pragma unroll
    for (int k = 0; k < 8; ++k) {
        segBase[t * 8 + k] = base;
        segPtr[t * 8 + k] = base;
        base += loc[k];
    }
    if (t == 255) segPtr[NSEG] = base;   // == E
}

// Scan step 3: add segment bases to every slab offset.
__global__ void k_scanC(unsigned* __restrict__ cnt, const unsigned* __restrict__ segBase) {
    int i = blockIdx.x * blockDim.x + threadIdx.x;
    if (i < NB * NSEG) cnt[i] += segBase[i & (NSEG - 1)];
}

// Pass B: re-read slab, place each edge in its (slab,segment) range via LDS
// cursors. Packed entry: (dstLocal<<14) | srcLocal  (9+14 = 23 bits).
__global__ void k_binfill(const int* __restrict__ idx, const int* __restrict__ flag,
                          const unsigned* __restrict__ cnt,
                          unsigned* __restrict__ binned, int E) {
    __shared__ unsigned cur[NSEG];    // 8 KB
    int tid = threadIdx.x;
    for (int i = tid; i < NSEG; i += 256) cur[i] = cnt[(size_t)blockIdx.x * NSEG + i];
    __syncthreads();
    const int mult = 1 + *flag;
    int slab = (E + NB - 1) / NB;
    int start = blockIdx.x * slab, end = min(E, start + slab);
    for (int e = start + tid; e < end; e += 256) {
        int s, d;
        if (mult == 2) { s = ((const int2*)idx)[e].x; d = ((const int2*)idx)[(size_t)E + e].x; }
        else           { s = idx[e];                  d = idx[(size_t)E + e]; }
        int seg = ((d >> DSTB_SHIFT) << 3) | (s >> SRC_SHIFT);
        unsigned pos = atomicAdd(&cur[seg], 1u);
        binned[pos] = ((unsigned)(d & (NPB - 1)) << SRC_SHIFT) | (unsigned)(s & ((1 << SRC_SHIFT) - 1));
    }
}

// Degree/dinv from bins: block = dst bucket; its 8 segments are contiguous.
__global__ void k_deg_dinv(const unsigned* __restrict__ segPtr,
                           const unsigned* __restrict__ binned,
                           float* __restrict__ dinv, int n) {
    __shared__ unsigned deg[NPB];
    int tid = threadIdx.x;
    int bb = blockIdx.x;
    for (int i = tid; i < NPB; i += 256) deg[i] = 0;
    __syncthreads();
    unsigned start = segPtr[bb * NSLICE], end = segPtr[bb * NSLICE + NSLICE];
    for (unsigned i = start + tid; i < end; i += 256)
        atomicAdd(&deg[binned[i] >> SRC_SHIFT], 1u);
    __syncthreads();
    int vbase = bb << DSTB_SHIFT;
    for (int lv = tid; lv < NPB; lv += 256) {
        int v = vbase + lv;
        if (v < n) dinv[v] = rsqrtf((float)(deg[lv] + 1u));   // +1 self-loop
    }
}

// g1[v][j] = dinv[v] * (x[v] . W1[:,j]); written to buf1 (gather source) AND
// buf2 (accumulator init = self-loop term).
__global__ void k_gemm1(const float* __restrict__ x, const float* __restrict__ W1,
                        const float* __restrict__ dinv,
                        float* __restrict__ g1, float* __restrict__ ginit, int n) {
    __shared__ float w1s[F_IN * F_HID];     // 8 KB
    __shared__ float xs[16][F_IN + 4];
    int tid = threadIdx.x;
    for (int i = tid; i < F_IN * F_HID; i += 256) w1s[i] = W1[i];
    int nb = blockIdx.x * 16;
    for (int q = tid; q < 512; q += 256) {
        int r = q >> 5, k4 = q & 31;
        int g = nb + r;
        float4 v = make_float4(0.f, 0.f, 0.f, 0.f);
        if (g < n) v = ((const float4*)x)[(size_t)g * 32 + k4];
        xs[r][k4 * 4 + 0] = v.x; xs[r][k4 * 4 + 1] = v.y;
        xs[r][k4 * 4 + 2] = v.z; xs[r][k4 * 4 + 3] = v.w;
    }
    __syncthreads();
    int r = tid >> 4, j = tid & 15;
    int g = nb + r;
    if (g < n) {
        float acc = 0.f;
#pragma unroll
        for (int k = 0; k < F_IN; ++k) acc += xs[r][k] * w1s[k * F_HID + j];
        float v = acc * dinv[g];
        size_t o = (size_t)g * F_HID + j;
        g1[o] = v;
        ginit[o] = v;
    }
}

// Segment-wise gather-aggregate. Block = (dst bucket, src slice); with the
// round-robin block->XCD mapping, slice = blockIdx&7 keeps each XCD's gathers
// inside one 1 MB slice of gin -> L2-resident. 16 lanes/edge read a full
// 64B gin row, LDS-atomic into acc[512][17], flush partials via atomicAdd.
__global__ void __launch_bounds__(512, 1)
k_agg(const unsigned* __restrict__ segPtr, const unsigned* __restrict__ binned,
      const float* __restrict__ gin, float* __restrict__ gacc, int n) {
    __shared__ float acc[NPB][F_HID + 1];   // 34.8 KB -> 4 blocks/CU
    int tid = threadIdx.x;
    unsigned start = segPtr[blockIdx.x], end = segPtr[blockIdx.x + 1];
    if (start == end) return;
    for (int q = tid; q < NPB * F_HID; q += 512)
        acc[q >> 4][q & 15] = 0.f;
    __syncthreads();
    int bb = blockIdx.x >> 3;
    int slice = blockIdx.x & (NSLICE - 1);
    const float* gs = gin + (((size_t)slice << SRC_SHIFT) * F_HID);
    int j = tid & 15;
#pragma unroll 2
    for (unsigned i = start + (tid >> 4); i < end; i += 32) {
        unsigned entry = binned[i];
        int sl = (int)(entry & ((1u << SRC_SHIFT) - 1));
        int dl = (int)(entry >> SRC_SHIFT);
        atomicAdd(&acc[dl][j], gs[(size_t)sl * F_HID + j]);
    }
    __syncthreads();
    int vbase = bb << DSTB_SHIFT;
    for (int q = tid; q < NPB * F_HID; q += 512) {
        float a = acc[q >> 4][q & 15];
        int v = vbase + (q >> 4);
        if (a != 0.f && v < n)
            atomicAdd(&gacc[(size_t)v * F_HID + (q & 15)], a);
    }
}

// Epilogues. RELU=1 (after layer-1 agg): g2 = relu(dinv*acc + b1)*dinv,
// written to both gout (gather src) and ginit (layer-2 accumulator init).
// RELU=0 (after layer-2 agg): gout = dinv*acc (feeds k_out).
template <int RELU>
__global__ void k_epi(const float* __restrict__ gacc, const float* __restrict__ dinv,
                      const float* __restrict__ b1,
                      float* __restrict__ gout, float* __restrict__ ginit, int n) {
    int i = blockIdx.x * blockDim.x + threadIdx.x;
    if (i < n * F_HID) {
        int v = i >> 4, j = i & 15;
        float di = dinv[v];
        if (RELU) {
            float h = fmaxf(di * gacc[i] + b1[j], 0.f) * di;
            gout[i] = h;
            ginit[i] = h;
        } else {
            gout[i] = di * gacc[i];
        }
    }
}

// out[v][c] = B[v] . W2[:,c] + b2[c]   (dinv already folded into B)
__global__ void k_out(const float* __restrict__ B,
                      const float* __restrict__ W2, const float* __restrict__ b2,
                      float* __restrict__ out, int n) {
    __shared__ float w2s[F_HID * F_OUT];
    __shared__ float b2s[F_OUT];
    int tid = threadIdx.x;
    for (int i = tid; i < F_HID * F_OUT; i += 256) w2s[i] = W2[i];
    if (tid < F_OUT) b2s[tid] = b2[tid];
    __syncthreads();
    int total = n * F_OUT;
    int stride = gridDim.x * blockDim.x;
    for (int i = blockIdx.x * blockDim.x + tid; i < total; i += stride) {
        int node = i / F_OUT, c = i - node * F_OUT;
        float acc = 0.f;
#pragma unroll
        for (int j = 0; j < F_HID; ++j) acc += B[(size_t)node * F_HID + j] * w2s[j * F_OUT + c];
        out[i] = acc + b2s[c];
    }
}

extern "C" void kernel_launch(void* const* d_in, const int* in_sizes, int n_in,
                              void* d_out, int out_size, void* d_ws, size_t ws_size,
                              hipStream_t stream) {
    const float* x   = (const float*)d_in[0];
    const int*   idx = (const int*)d_in[1];
    const float* W1  = (const float*)d_in[2];
    const float* b1  = (const float*)d_in[3];
    const float* W2  = (const float*)d_in[4];
    const float* b2  = (const float*)d_in[5];
    float* out = (float*)d_out;

    const int n = in_sizes[0] / F_IN;       // 100000
    const int E = in_sizes[1] / 2;          // 6400000

    char* ws = (char*)d_ws;
    size_t off = 0;
    auto carve = [&](size_t bytes) { char* p = ws + off; off += (bytes + 255) / 256 * 256; return p; };
    int*      flag    = (int*)carve(4);
    float*    dinv    = (float*)carve((size_t)n * 4);
    unsigned* segPtr  = (unsigned*)carve((NSEG + 1) * 4);
    unsigned* segTot  = (unsigned*)carve(NSEG * 4);
    unsigned* segBase = (unsigned*)carve(NSEG * 4);
    float*    buf1    = (float*)carve((size_t)n * F_HID * 4);   // gather src
    float*    buf2    = (float*)carve((size_t)n * F_HID * 4);   // accumulator
    // binned (25.6 MB) + cnt (2 MB) live in d_out (55.2 MB); both fully
    // consumed before k_out writes d_out.
    unsigned* binned = (unsigned*)d_out;
    unsigned* cnt    = binned + (size_t)E;

    const int B = 256;
    const int nbEpi = (n * F_HID + B - 1) / B;
    k_detect  <<<1, B, 0, stream>>>(idx, flag);
    k_bincount<<<NB, B, 0, stream>>>(idx, flag, cnt, E);
    k_scanA   <<<NSEG / B, B, 0, stream>>>(cnt, segTot);
    k_scanB   <<<1, B, 0, stream>>>(segTot, segBase, segPtr);
    k_scanC   <<<(NB * NSEG + B - 1) / B, B, 0, stream>>>(cnt, segBase);
    k_binfill <<<NB, B, 0, stream>>>(idx, flag, cnt, binned, E);
    k_deg_dinv<<<NDSTB, B, 0, stream>>>(segPtr, binned, dinv, n);
    k_gemm1   <<<(n + 15) / 16, B, 0, stream>>>(x, W1, dinv, buf1, buf2, n);
    k_agg     <<<NSEG, 512, 0, stream>>>(segPtr, binned, buf1, buf2, n);
    k_epi<1>  <<<nbEpi, B, 0, stream>>>(buf2, dinv, b1, buf1, buf2, n);
    k_agg     <<<NSEG, 512, 0, stream>>>(segPtr, binned, buf1, buf2, n);
    k_epi<0>  <<<nbEpi, B, 0, stream>>>(buf2, dinv, b1, buf1, buf1, n);
    k_out     <<<8192, B, 0, stream>>>(buf1, W2, b2, out, n);
}

// Round 6
// 401.208 us; speedup vs baseline: 4.3947x; 4.3947x over previous
//
#include <hip/hip_runtime.h>
#include <cstdint>

#define F_IN  128
#define F_HID 16
#define F_OUT 138
#define NBUCK 256        // dst buckets
#define NPB_SHIFT 9
#define NPB 512          // nodes per bucket
#define NB  256          // edge slabs (= blocks) for binning passes

// ---------------------------------------------------------------------------
// Detect edge_index dtype: int64 (LE, values < 2^31) -> every odd int32 word
// is zero. flag = 1 -> int64 (stride 2 int32 words), 0 -> int32.
__global__ void k_detect(const int* __restrict__ idx, int* __restrict__ flag) {
    __shared__ int nz;
    if (threadIdx.x == 0) nz = 0;
    __syncthreads();
    for (int i = threadIdx.x; i < 1024; i += blockDim.x)
        if (idx[2 * i + 1] != 0) nz = 1;
    __syncthreads();
    if (threadIdx.x == 0) *flag = (nz == 0) ? 1 : 0;
}

// Pass A: per-block LDS histogram of dst-buckets over this block's edge slab.
__global__ void k_bincount(const int* __restrict__ idx, const int* __restrict__ flag,
                           unsigned* __restrict__ cnt, int E) {
    __shared__ unsigned hist[NBUCK];
    int tid = threadIdx.x;
    for (int i = tid; i < NBUCK; i += 256) hist[i] = 0;
    __syncthreads();
    const int mult = 1 + *flag;
    int slab = (E + NB - 1) / NB;
    int start = blockIdx.x * slab, end = min(E, start + slab);
    if (mult == 2) {
        for (int e = start + tid; e < end; e += 256) {
            int d = ((const int2*)idx)[(size_t)E + e].x;
            atomicAdd(&hist[d >> NPB_SHIFT], 1u);
        }
    } else {
        for (int e = start + tid; e < end; e += 256) {
            int d = idx[(size_t)E + e];
            atomicAdd(&hist[d >> NPB_SHIFT], 1u);
        }
    }
    __syncthreads();
    for (int i = tid; i < NBUCK; i += 256) cnt[(size_t)i * NB + blockIdx.x] = hist[i];
}

// Scan cnt[bucket][block] -> exclusive offsets; emits bucketPtr[].
__global__ void k_scan(unsigned* __restrict__ cnt, unsigned* __restrict__ bucketPtr, int E) {
    __shared__ unsigned tot[NBUCK];
    int t = threadIdx.x;
    unsigned run = 0;
    for (int b = 0; b < NB; ++b) {
        unsigned c = cnt[(size_t)t * NB + b];
        cnt[(size_t)t * NB + b] = run;
        run += c;
    }
    tot[t] = run;
    __syncthreads();
    if (t == 0) {
        unsigned r = 0;
        for (int i = 0; i < NBUCK; ++i) { unsigned c = tot[i]; tot[i] = r; bucketPtr[i] = r; r += c; }
        bucketPtr[NBUCK] = r;   // == E
    }
    __syncthreads();
    unsigned base = tot[t];
    for (int b = 0; b < NB; ++b) cnt[(size_t)t * NB + b] += base;
}

// Pass B: re-read slab, place each edge in its (block,bucket) segment via LDS
// cursors. Packed entry: (dstLocal<<17) | src  (9+17 = 26 bits, src < 2^17).
__global__ void k_binfill(const int* __restrict__ idx, const int* __restrict__ flag,
                          const unsigned* __restrict__ cnt,
                          unsigned* __restrict__ binned, int E) {
    __shared__ unsigned cur[NBUCK];
    int tid = threadIdx.x;
    for (int i = tid; i < NBUCK; i += 256) cur[i] = cnt[(size_t)i * NB + blockIdx.x];
    __syncthreads();
    const int mult = 1 + *flag;
    int slab = (E + NB - 1) / NB;
    int start = blockIdx.x * slab, end = min(E, start + slab);
    for (int e = start + tid; e < end; e += 256) {
        int s, d;
        if (mult == 2) { s = ((const int2*)idx)[e].x; d = ((const int2*)idx)[(size_t)E + e].x; }
        else           { s = idx[e];                  d = idx[(size_t)E + e]; }
        unsigned pos = atomicAdd(&cur[d >> NPB_SHIFT], 1u);
        binned[pos] = ((unsigned)(d & (NPB - 1)) << 17) | (unsigned)s;
    }
}

// Per bucket: degree histogram -> LDS exclusive scan -> exact CSR ptr[] and
// dinv[]. Bucket's CSR base == bucketPtr[bb] (binned is bucket-ordered).
__global__ void k_ptr(const unsigned* __restrict__ bucketPtr,
                      const unsigned* __restrict__ binned,
                      unsigned* __restrict__ ptr, float* __restrict__ dinv,
                      int n, int E) {
    __shared__ unsigned deg[NPB];
    __shared__ unsigned sh[256];
    int tid = threadIdx.x;
    int bb = blockIdx.x;
    for (int i = tid; i < NPB; i += 256) deg[i] = 0;
    __syncthreads();
    unsigned start = bucketPtr[bb], end = bucketPtr[bb + 1];
    for (unsigned i = start + tid; i < end; i += 256)
        atomicAdd(&deg[binned[i] >> 17], 1u);
    __syncthreads();
    unsigned d0 = deg[2 * tid], d1 = deg[2 * tid + 1];
    unsigned pair = d0 + d1;
    sh[tid] = pair;
    __syncthreads();
    for (int off = 1; off < 256; off <<= 1) {
        unsigned v = (tid >= off) ? sh[tid - off] : 0u;
        __syncthreads();
        sh[tid] += v;
        __syncthreads();
    }
    unsigned excl = sh[tid] - pair;   // exclusive prefix of this pair
    int v0 = (bb << NPB_SHIFT) + 2 * tid;
    if (v0 < n) {
        ptr[v0] = start + excl;
        dinv[v0] = rsqrtf((float)(d0 + 1u));
    }
    if (v0 + 1 < n) {
        ptr[v0 + 1] = start + excl + d0;
        dinv[v0 + 1] = rsqrtf((float)(d1 + 1u));
    }
    if (bb == 0 && tid == 0) ptr[n] = (unsigned)E;
}

// Re-scatter bucket segment into CSR order. Writes land in the bucket's own
// ~130 KB col window -> L2-resident, no global write-allocate blowup.
__global__ void k_fill2(const unsigned* __restrict__ bucketPtr,
                        const unsigned* __restrict__ binned,
                        const unsigned* __restrict__ ptr,
                        int* __restrict__ col, int n) {
    __shared__ unsigned cur[NPB];
    int tid = threadIdx.x;
    int bb = blockIdx.x;
    int vbase = bb << NPB_SHIFT;
    for (int i = tid; i < NPB; i += 256) {
        int v = vbase + i;
        cur[i] = (v < n) ? ptr[v] : 0u;
    }
    __syncthreads();
    unsigned start = bucketPtr[bb], end = bucketPtr[bb + 1];
    for (unsigned i = start + tid; i < end; i += 256) {
        unsigned entry = binned[i];
        unsigned pos = atomicAdd(&cur[entry >> 17], 1u);
        col[pos] = (int)(entry & 0x1FFFFu);
    }
}

// g1[v][j] = dinv[v] * (x[v] . W1[:,j]).  16 nodes x 16 feats per block.
__global__ void k_gemm1(const float* __restrict__ x, const float* __restrict__ W1,
                        const float* __restrict__ dinv,
                        float* __restrict__ g1, int n) {
    __shared__ float w1s[F_IN * F_HID];     // 8 KB
    __shared__ float xs[16][F_IN + 4];
    int tid = threadIdx.x;
    for (int i = tid; i < F_IN * F_HID; i += 256) w1s[i] = W1[i];
    int nb = blockIdx.x * 16;
    for (int q = tid; q < 512; q += 256) {
        int r = q >> 5, k4 = q & 31;
        int g = nb + r;
        float4 v = make_float4(0.f, 0.f, 0.f, 0.f);
        if (g < n) v = ((const float4*)x)[(size_t)g * 32 + k4];
        xs[r][k4 * 4 + 0] = v.x; xs[r][k4 * 4 + 1] = v.y;
        xs[r][k4 * 4 + 2] = v.z; xs[r][k4 * 4 + 3] = v.w;
    }
    __syncthreads();
    int r = tid >> 4, j = tid & 15;
    int g = nb + r;
    if (g < n) {
        float acc = 0.f;
#pragma unroll
        for (int k = 0; k < F_IN; ++k) acc += xs[r][k] * w1s[k * F_HID + j];
        g1[(size_t)g * F_HID + j] = acc * dinv[g];
    }
}

// Pull-mode CSR aggregation. 16 lanes per node; 8-way unrolled independent
// gathers for MLP; no LDS, no atomics -> full occupancy. Self-loop = init.
// Fused epilogue: RELU=1: gout = relu(dinv*acc + b1)*dinv; RELU=0: dinv*acc.
template <int RELU>
__global__ void k_agg(const unsigned* __restrict__ ptr, const int* __restrict__ col,
                      const float* __restrict__ gin, float* __restrict__ gout,
                      const float* __restrict__ dinv, const float* __restrict__ b1,
                      int n) {
    int t = blockIdx.x * blockDim.x + threadIdx.x;
    int v = t >> 4, j = t & 15;
    if (v >= n) return;
    float acc = gin[(size_t)v * F_HID + j];   // self-loop
    unsigned i = ptr[v], end = ptr[v + 1];
    for (; i + 8 <= end; i += 8) {
        int u0 = col[i],     u1 = col[i + 1], u2 = col[i + 2], u3 = col[i + 3];
        int u4 = col[i + 4], u5 = col[i + 5], u6 = col[i + 6], u7 = col[i + 7];
        float a0 = gin[(size_t)u0 * F_HID + j];
        float a1 = gin[(size_t)u1 * F_HID + j];
        float a2 = gin[(size_t)u2 * F_HID + j];
        float a3 = gin[(size_t)u3 * F_HID + j];
        float a4 = gin[(size_t)u4 * F_HID + j];
        float a5 = gin[(size_t)u5 * F_HID + j];
        float a6 = gin[(size_t)u6 * F_HID + j];
        float a7 = gin[(size_t)u7 * F_HID + j];
        acc += ((a0 + a1) + (a2 + a3)) + ((a4 + a5) + (a6 + a7));
    }
    for (; i < end; ++i) acc += gin[(size_t)col[i] * F_HID + j];
    float di = dinv[v];
    if (RELU) gout[(size_t)v * F_HID + j] = fmaxf(di * acc + b1[j], 0.f) * di;
    else      gout[(size_t)v * F_HID + j] = di * acc;
}

// out[v][c] = B[v] . W2[:,c] + b2[c]   (dinv already folded into B)
__global__ void k_out(const float* __restrict__ B,
                      const float* __restrict__ W2, const float* __restrict__ b2,
                      float* __restrict__ out, int n) {
    __shared__ float w2s[F_HID * F_OUT];
    __shared__ float b2s[F_OUT];
    int tid = threadIdx.x;
    for (int i = tid; i < F_HID * F_OUT; i += 256) w2s[i] = W2[i];
    if (tid < F_OUT) b2s[tid] = b2[tid];
    __syncthreads();
    int total = n * F_OUT;
    int stride = gridDim.x * blockDim.x;
    for (int i = blockIdx.x * blockDim.x + tid; i < total; i += stride) {
        int node = i / F_OUT, c = i - node * F_OUT;
        float acc = 0.f;
#pragma unroll
        for (int j = 0; j < F_HID; ++j) acc += B[(size_t)node * F_HID + j] * w2s[j * F_OUT + c];
        out[i] = acc + b2s[c];
    }
}

extern "C" void kernel_launch(void* const* d_in, const int* in_sizes, int n_in,
                              void* d_out, int out_size, void* d_ws, size_t ws_size,
                              hipStream_t stream) {
    const float* x   = (const float*)d_in[0];
    const int*   idx = (const int*)d_in[1];
    const float* W1  = (const float*)d_in[2];
    const float* b1  = (const float*)d_in[3];
    const float* W2  = (const float*)d_in[4];
    const float* b2  = (const float*)d_in[5];
    float* out = (float*)d_out;

    const int n = in_sizes[0] / F_IN;       // 100000
    const int E = in_sizes[1] / 2;          // 6400000

    char* ws = (char*)d_ws;
    size_t off = 0;
    auto carve = [&](size_t bytes) { char* p = ws + off; off += (bytes + 255) / 256 * 256; return p; };
    int*      flag      = (int*)carve(4);
    float*    dinv      = (float*)carve((size_t)n * 4);
    unsigned* bucketPtr = (unsigned*)carve((NBUCK + 1) * 4);
    unsigned* cnt       = (unsigned*)carve((size_t)NBUCK * NB * 4);   // 256 KB
    unsigned* ptr       = (unsigned*)carve(((size_t)n + 1) * 4);
    float*    buf1      = (float*)carve((size_t)n * F_HID * 4);       // g buffers
    float*    buf2      = (float*)carve((size_t)n * F_HID * 4);
    // binned (E words = 25.6 MB) and col (E words) both live in d_out
    // (55.2 MB); both fully consumed before k_out overwrites d_out.
    unsigned* binned = (unsigned*)d_out;
    int*      col    = (int*)d_out + (size_t)E;

    const int B = 256;
    k_detect  <<<1, B, 0, stream>>>(idx, flag);
    k_bincount<<<NB, B, 0, stream>>>(idx, flag, cnt, E);
    k_scan    <<<1, NBUCK, 0, stream>>>(cnt, bucketPtr, E);
    k_binfill <<<NB, B, 0, stream>>>(idx, flag, cnt, binned, E);
    k_ptr     <<<NBUCK, B, 0, stream>>>(bucketPtr, binned, ptr, dinv, n, E);
    k_fill2   <<<NBUCK, B, 0, stream>>>(bucketPtr, binned, ptr, col, n);
    k_gemm1   <<<(n + 15) / 16, B, 0, stream>>>(x, W1, dinv, buf1, n);
    k_agg<1>  <<<(n * F_HID + B - 1) / B, B, 0, stream>>>(ptr, col, buf1, buf2, dinv, b1, n);
    k_agg<0>  <<<(n * F_HID + B - 1) / B, B, 0, stream>>>(ptr, col, buf2, buf1, dinv, b1, n);
    k_out     <<<8192, B, 0, stream>>>(buf1, W2, b2, out, n);
}